// Round 1
// 10018.701 us; speedup vs baseline: 1.2143x; 1.2143x over previous
//
#include <hip/hip_runtime.h>

typedef __attribute__((ext_vector_type(8))) short short8;
typedef __attribute__((ext_vector_type(4))) float f32x4;

#define D_DIM 1024
#define H_DIM 1024
#define FH 4096
#define NB 64
#define TT 512
#define MROWS (NB * TT)   // 32768
#define SCAN_BLOCKS 128

__device__ __forceinline__ ushort f2bf(float f) {
  union { float f; unsigned u; } v; v.f = f;
  unsigned u = v.u;
  return (ushort)((u + 0x7FFFu + ((u >> 16) & 1u)) >> 16);
}
__device__ __forceinline__ float bf2f(ushort h) {
  union { unsigned u; float f; } v; v.u = ((unsigned)h) << 16;
  return v.f;
}

// ---------------------------------------------------------------------------
// Transpose + fp32->bf16 convert + gate-interleaved column permutation.
// W: [1024][4096] row-major.  WT row r = b*32 + hc_local*4 + gate  maps to
// original column  oc = gate*1024 + b*8 + hc_local.  WT: [4096][1024] bf16.
// grid (64, 16), block 256.
// ---------------------------------------------------------------------------
__global__ void transpose_perm(const float* __restrict__ W, ushort* __restrict__ WT) {
  __shared__ ushort tile[64][65];
  int ocTile = blockIdx.x * 64;
  int kTile  = blockIdx.y * 64;
  int tx = threadIdx.x & 63, ty = threadIdx.x >> 6;
  #pragma unroll
  for (int i = 0; i < 16; ++i) {
    int r = ty + i * 4;  // k offset
    float v = W[(size_t)(kTile + r) * FH + ocTile + tx];
    tile[r][tx] = f2bf(v);
  }
  __syncthreads();
  #pragma unroll
  for (int i = 0; i < 16; ++i) {
    int c = ty + i * 4;              // column offset within tile
    int oc = ocTile + c;
    int gate = oc >> 10, rem = oc & 1023;
    int b = rem >> 3, hcl = rem & 7;
    int r_out = b * 32 + hcl * 4 + gate;
    WT[(size_t)r_out * D_DIM + kTile + tx] = tile[tx][c];
  }
}

// x fp32 -> bf16, one float4 per thread. grid 32768, block 256.
__global__ void cvt_x(const float* __restrict__ x, ushort* __restrict__ xb) {
  size_t i = (size_t)blockIdx.x * blockDim.x + threadIdx.x;
  const float4* x4 = (const float4*)x;
  float4 v = x4[i];
  ushort4 o; o.x = f2bf(v.x); o.y = f2bf(v.y); o.z = f2bf(v.z); o.w = f2bf(v.w);
  ((ushort4*)xb)[i] = o;
}

// h0 fp32 -> bf16 into h_buf0. grid 256, block 256.
__global__ void cvt_h0(const float* __restrict__ h0, ushort* __restrict__ hb) {
  int i = blockIdx.x * blockDim.x + threadIdx.x;
  hb[i] = f2bf(h0[i]);
}

// zero the grid-barrier counter (runs after gemm_xz, which reads this region).
__global__ void zero_cnt(unsigned* c) { *c = 0u; }

// ---------------------------------------------------------------------------
// xz GEMM: A = x_bf16 [32768][1024], B = WxT_perm [4096][1024] (both K-contig)
// C written bf16 into xz[t][n][4096] layout (row m = n*512+t scattered).
// 128x128 tile, BK=64, 256 threads (4 waves as 2x2 of 64x64).
// ---------------------------------------------------------------------------
__global__ __launch_bounds__(256) void gemm_xz(const ushort* __restrict__ A,
                                               const ushort* __restrict__ B,
                                               ushort* __restrict__ xz) {
  __shared__ ushort As[128][72];
  __shared__ ushort Bs[128][72];
  int bid = blockIdx.x;
  int nb = bid & 31, mb = bid >> 5;
  int m0 = mb * 128, n0 = nb * 128;
  int tid = threadIdx.x;
  int lane = tid & 63, w = tid >> 6;
  int wm = w >> 1, wn = w & 1;
  int quad = lane >> 4, l15 = lane & 15;

  f32x4 acc[4][4];
  #pragma unroll
  for (int i = 0; i < 4; ++i)
    #pragma unroll
    for (int j = 0; j < 4; ++j) acc[i][j] = (f32x4)0.f;

  for (int k0 = 0; k0 < D_DIM; k0 += 64) {
    #pragma unroll
    for (int q = 0; q < 4; ++q) {
      int seg = q * 256 + tid;          // 0..1023
      int row = seg >> 3, k8 = seg & 7;
      uint4 va = *(const uint4*)(A + (size_t)(m0 + row) * D_DIM + k0 + k8 * 8);
      *(uint4*)(&As[row][k8 * 8]) = va;
      uint4 vb = *(const uint4*)(B + (size_t)(n0 + row) * D_DIM + k0 + k8 * 8);
      *(uint4*)(&Bs[row][k8 * 8]) = vb;
    }
    __syncthreads();
    #pragma unroll
    for (int kc = 0; kc < 2; ++kc) {
      int krow = kc * 32 + quad * 8;
      short8 a[4], b[4];
      #pragma unroll
      for (int mt = 0; mt < 4; ++mt)
        a[mt] = *(const short8*)(&As[wm * 64 + mt * 16 + l15][krow]);
      #pragma unroll
      for (int nt = 0; nt < 4; ++nt)
        b[nt] = *(const short8*)(&Bs[wn * 64 + nt * 16 + l15][krow]);
      #pragma unroll
      for (int mt = 0; mt < 4; ++mt)
        #pragma unroll
        for (int nt = 0; nt < 4; ++nt)
          acc[mt][nt] = __builtin_amdgcn_mfma_f32_16x16x32_bf16(a[mt], b[nt], acc[mt][nt], 0, 0, 0);
    }
    __syncthreads();
  }
  // epilogue: write bf16 into [t][n][4096]
  #pragma unroll
  for (int mt = 0; mt < 4; ++mt)
    #pragma unroll
    for (int nt = 0; nt < 4; ++nt)
      #pragma unroll
      for (int r = 0; r < 4; ++r) {
        int m = m0 + wm * 64 + mt * 16 + quad * 4 + r;
        int n = n0 + wn * 64 + nt * 16 + l15;
        int t = m & 511, nn = m >> 9;
        xz[(size_t)(t * 64 + nn) * FH + n] = f2bf(acc[mt][nt][r]);
      }
}

// ---------------------------------------------------------------------------
// Persistent cooperative LSTM scan.
// 128 blocks x 256 threads. Block owns 32 permuted gate-cols (8 h-cols).
// Wave w holds Wh B-fragments for K-slice [w*256,(w+1)*256) in registers.
// Per step: z_partial = h_prev @ Wh_slice (MFMA, A-frags direct from global),
// K-reduce + gate exchange via LDS, gates in fp32, c in registers,
// h written bf16 (recurrence) + fp32 (output).
//
// Cross-block exchange uses agent-scope relaxed atomics only:
//   - h stores/loads are sc0|sc1 dword atomics (always served at the L3
//     coherence point -> no buffer_wbl2 / buffer_inv per step).
//   - barrier = monotonic counter; release ordering = explicit
//     s_waitcnt vmcnt(0) draining the write-through h stores before arrival.
// This replaces cg::grid.sync()'s full L2 writeback+invalidate per step.
// ---------------------------------------------------------------------------
__global__ __launch_bounds__(256, 1) void lstm_scan(
    const ushort* __restrict__ xz,    // [512][64][4096] bf16 (permuted cols)
    const ushort* __restrict__ WhT,   // [4096][1024] bf16 (permuted rows)
    const float*  __restrict__ bias,  // [4096] original order
    ushort* h0buf, ushort* h1buf,     // [64][1024] bf16 ping-pong
    float* __restrict__ out,          // [64][512][1024] fp32
    unsigned* cnt)                    // grid-barrier counter (pre-zeroed)
{
  __shared__ float zpart[4 * 64 * 32];
  const int blk = blockIdx.x;     // 0..127
  const int tid = threadIdx.x;
  const int w = tid >> 6;         // wave = K-slice 0..3
  const int lane = tid & 63;
  const int quad = lane >> 4;
  const int l15 = lane & 15;

  // B fragments (Wh slice) -> registers: [nt][kc], K-offset = w*256+kc*32
  short8 bfrag[2][8];
  {
    const ushort* base = WhT + (size_t)(blk * 32) * D_DIM + w * 256;
    #pragma unroll
    for (int nt = 0; nt < 2; ++nt)
      #pragma unroll
      for (int kc = 0; kc < 8; ++kc)
        bfrag[nt][kc] = *(const short8*)(base + (size_t)(nt * 16 + l15) * D_DIM + kc * 32 + quad * 8);
  }

  // gate-phase assignment: thread -> (m = tid>>2, col-quad = tid&3)
  const int gm = tid >> 2;
  const int gq = tid & 3;
  float bb[8];
  #pragma unroll
  for (int j = 0; j < 8; ++j) {
    int c = gq * 8 + j;
    int gate = c & 3, hcl = c >> 2;
    bb[j] = bias[gate * 1024 + blk * 8 + hcl];
  }
  float cst[2] = {0.f, 0.f};

  const ushort* bufs[2] = {h0buf, h1buf};

  for (int t = 0; t < TT; ++t) {
    const ushort* rb = bufs[t & 1];
    ushort* wb = (ushort*)bufs[(t + 1) & 1];

    // prefetch xz for this thread's gate-phase cols (hidden under GEMM)
    uint4 xzv = *(const uint4*)(xz + (size_t)(t * 64 + gm) * FH + blk * 32 + gq * 8);

    f32x4 acc[4][2];
    #pragma unroll
    for (int mt = 0; mt < 4; ++mt) { acc[mt][0] = (f32x4)0.f; acc[mt][1] = (f32x4)0.f; }

    #pragma unroll
    for (int kc = 0; kc < 8; ++kc) {
      const ushort* ab = rb + w * 256 + kc * 32 + quad * 8;
      short8 a[4];
      #pragma unroll
      for (int mt = 0; mt < 4; ++mt) {
        const unsigned* ap = (const unsigned*)(ab + (size_t)(mt * 16 + l15) * H_DIM);
        union { unsigned u[4]; short8 s; } av;
        #pragma unroll
        for (int j = 0; j < 4; ++j)
          av.u[j] = __hip_atomic_load((unsigned*)(ap + j), __ATOMIC_RELAXED, __HIP_MEMORY_SCOPE_AGENT);
        a[mt] = av.s;
      }
      #pragma unroll
      for (int mt = 0; mt < 4; ++mt) {
        acc[mt][0] = __builtin_amdgcn_mfma_f32_16x16x32_bf16(a[mt], bfrag[0][kc], acc[mt][0], 0, 0, 0);
        acc[mt][1] = __builtin_amdgcn_mfma_f32_16x16x32_bf16(a[mt], bfrag[1][kc], acc[mt][1], 0, 0, 0);
      }
    }

    // write K-partials to LDS: zpart[w][m][col]
    #pragma unroll
    for (int mt = 0; mt < 4; ++mt)
      #pragma unroll
      for (int nt = 0; nt < 2; ++nt)
        #pragma unroll
        for (int r = 0; r < 4; ++r) {
          int m = mt * 16 + quad * 4 + r;
          int col = nt * 16 + l15;
          zpart[(w * 64 + m) * 32 + col] = acc[mt][nt][r];
        }
    __syncthreads();

    // gate phase: 8 cols per thread = 2 h-cols x 4 gates
    float z[8];
    {
      const ushort* xp = (const ushort*)&xzv;
      #pragma unroll
      for (int j = 0; j < 8; ++j) z[j] = bb[j] + bf2f(xp[j]);
      #pragma unroll
      for (int wv = 0; wv < 4; ++wv) {
        const float4* pp = (const float4*)&zpart[(wv * 64 + gm) * 32 + gq * 8];
        float4 p0 = pp[0], p1 = pp[1];
        z[0] += p0.x; z[1] += p0.y; z[2] += p0.z; z[3] += p0.w;
        z[4] += p1.x; z[5] += p1.y; z[6] += p1.z; z[7] += p1.w;
      }
    }
    ushort hpack[2];
    float hout[2];
    #pragma unroll
    for (int p = 0; p < 2; ++p) {
      float ai = z[p * 4 + 0], af = z[p * 4 + 1], ao = z[p * 4 + 2], ag = z[p * 4 + 3];
      float ig = 1.f / (1.f + __expf(-ai));
      float fg = 1.f / (1.f + __expf(-af));
      float og = 1.f / (1.f + __expf(-ao));
      float gg = 2.f / (1.f + __expf(-2.f * ag)) - 1.f;   // tanh
      float c = fg * cst[p] + ig * gg;
      cst[p] = c;
      float th = 2.f / (1.f + __expf(-2.f * c)) - 1.f;    // tanh
      float h = og * th;
      hout[p] = h; hpack[p] = f2bf(h);
    }
    // h recurrence store: agent-scope write-through dword (reaches L3)
    unsigned hbits = (unsigned)hpack[0] | ((unsigned)hpack[1] << 16);
    __hip_atomic_store((unsigned*)(wb + (size_t)gm * H_DIM + blk * 8 + gq * 2), hbits,
                       __ATOMIC_RELAXED, __HIP_MEMORY_SCOPE_AGENT);
    // output store: plain (nobody reads it during the scan)
    float2 ho; ho.x = hout[0]; ho.y = hout[1];
    *(float2*)(out + ((size_t)gm * TT + t) * H_DIM + blk * 8 + gq * 2) = ho;

    // --- lightweight grid barrier (no L2 writeback/invalidate) ---
    // Drain this thread's coherent h stores to the L3 coherence point,
    // then one arrival per block; single poller, relaxed loads.
    asm volatile("s_waitcnt vmcnt(0)" ::: "memory");
    __syncthreads();
    if (tid == 0) {
      __hip_atomic_fetch_add(cnt, 1u, __ATOMIC_RELAXED, __HIP_MEMORY_SCOPE_AGENT);
      const unsigned tgt = (unsigned)SCAN_BLOCKS * (unsigned)(t + 1);
      while (__hip_atomic_load(cnt, __ATOMIC_RELAXED, __HIP_MEMORY_SCOPE_AGENT) < tgt) {}
    }
    __syncthreads();
  }
}

// ---------------------------------------------------------------------------
extern "C" void kernel_launch(void* const* d_in, const int* in_sizes, int n_in,
                              void* d_out, int out_size, void* d_ws, size_t ws_size,
                              hipStream_t stream) {
  const float* x  = (const float*)d_in[0];   // 64*512*1024
  const float* h0 = (const float*)d_in[1];   // 64*1024
  const float* Wx = (const float*)d_in[2];   // 1024*4096
  const float* Wh = (const float*)d_in[3];   // 1024*4096
  const float* b  = (const float*)d_in[4];   // 4096
  float* out = (float*)d_out;

  char* ws = (char*)d_ws;
  ushort* xz    = (ushort*)(ws + 0);                    // 268,435,456 B
  ushort* xb    = (ushort*)(ws + 268435456);            //  67,108,864 B (dead after gemm_xz)
  ushort* WxT   = (ushort*)(ws + 335544320);            //   8,388,608 B
  ushort* WhT   = (ushort*)(ws + 343932928);            //   8,388,608 B
  ushort* h0buf = (ushort*)(ws + 352321536);            //     131,072 B
  ushort* h1buf = (ushort*)(ws + 352452608);            //     131,072 B
  unsigned* cnt = (unsigned*)(ws + 268435456);          // aliases xb (dead by scan time)

  transpose_perm<<<dim3(64, 16), 256, 0, stream>>>(Wx, WxT);
  transpose_perm<<<dim3(64, 16), 256, 0, stream>>>(Wh, WhT);
  cvt_x<<<32768, 256, 0, stream>>>(x, xb);
  cvt_h0<<<256, 256, 0, stream>>>(h0, h0buf);
  gemm_xz<<<8192, 256, 0, stream>>>(xb, WxT, xz);
  zero_cnt<<<1, 1, 0, stream>>>(cnt);   // after gemm_xz: xb region is dead

  void* args[] = {(void*)&xz, (void*)&WhT, (void*)&b, (void*)&h0buf, (void*)&h1buf,
                  (void*)&out, (void*)&cnt};
  hipLaunchCooperativeKernel((const void*)lstm_scan, dim3(SCAN_BLOCKS), dim3(256), args, 0, stream);
}

// Round 3
// 5857.586 us; speedup vs baseline: 2.0769x; 1.7104x over previous
//
#include <hip/hip_runtime.h>

typedef __attribute__((ext_vector_type(8))) short short8;
typedef __attribute__((ext_vector_type(4))) float f32x4;
typedef unsigned long long ull;

#define D_DIM 1024
#define H_DIM 1024
#define FH 4096
#define NB 64
#define TT 512
#define MROWS (NB * TT)   // 32768
#define SCAN_BLOCKS 128

__device__ __forceinline__ ushort f2bf(float f) {
  union { float f; unsigned u; } v; v.f = f;
  unsigned u = v.u;
  return (ushort)((u + 0x7FFFu + ((u >> 16) & 1u)) >> 16);
}
__device__ __forceinline__ float bf2f(ushort h) {
  union { unsigned u; float f; } v; v.u = ((unsigned)h) << 16;
  return v.f;
}

// ---------------------------------------------------------------------------
// Transpose + fp32->bf16 convert + gate-interleaved column permutation.
// ---------------------------------------------------------------------------
__global__ void transpose_perm(const float* __restrict__ W, ushort* __restrict__ WT) {
  __shared__ ushort tile[64][65];
  int ocTile = blockIdx.x * 64;
  int kTile  = blockIdx.y * 64;
  int tx = threadIdx.x & 63, ty = threadIdx.x >> 6;
  #pragma unroll
  for (int i = 0; i < 16; ++i) {
    int r = ty + i * 4;  // k offset
    float v = W[(size_t)(kTile + r) * FH + ocTile + tx];
    tile[r][tx] = f2bf(v);
  }
  __syncthreads();
  #pragma unroll
  for (int i = 0; i < 16; ++i) {
    int c = ty + i * 4;              // column offset within tile
    int oc = ocTile + c;
    int gate = oc >> 10, rem = oc & 1023;
    int b = rem >> 3, hcl = rem & 7;
    int r_out = b * 32 + hcl * 4 + gate;
    WT[(size_t)r_out * D_DIM + kTile + tx] = tile[tx][c];
  }
}

// x fp32 -> bf16, one float4 per thread. grid 32768, block 256.
__global__ void cvt_x(const float* __restrict__ x, ushort* __restrict__ xb) {
  size_t i = (size_t)blockIdx.x * blockDim.x + threadIdx.x;
  const float4* x4 = (const float4*)x;
  float4 v = x4[i];
  ushort4 o; o.x = f2bf(v.x); o.y = f2bf(v.y); o.z = f2bf(v.z); o.w = f2bf(v.w);
  ((ushort4*)xb)[i] = o;
}

// h0 fp32 -> bf16 into h_buf0. grid 256, block 256.
__global__ void cvt_h0(const float* __restrict__ h0, ushort* __restrict__ hb) {
  int i = blockIdx.x * blockDim.x + threadIdx.x;
  hb[i] = f2bf(h0[i]);
}

// zero the barrier arrival flags (runs after gemm_xz, which reads this region).
// flags: arrive[i*32], i = 0..127 (one 128B line per block).
__global__ void zero_flags(unsigned* f) { f[threadIdx.x * 32] = 0u; }

// ---------------------------------------------------------------------------
// xz GEMM: A = x_bf16 [32768][1024], B = WxT_perm [4096][1024] (both K-contig)
// 128x128 tile, BK=64, 256 threads (4 waves as 2x2 of 64x64).
// ---------------------------------------------------------------------------
__global__ __launch_bounds__(256) void gemm_xz(const ushort* __restrict__ A,
                                               const ushort* __restrict__ B,
                                               ushort* __restrict__ xz) {
  __shared__ ushort As[128][72];
  __shared__ ushort Bs[128][72];
  int bid = blockIdx.x;
  int nb = bid & 31, mb = bid >> 5;
  int m0 = mb * 128, n0 = nb * 128;
  int tid = threadIdx.x;
  int lane = tid & 63, w = tid >> 6;
  int wm = w >> 1, wn = w & 1;
  int quad = lane >> 4, l15 = lane & 15;

  f32x4 acc[4][4];
  #pragma unroll
  for (int i = 0; i < 4; ++i)
    #pragma unroll
    for (int j = 0; j < 4; ++j) acc[i][j] = (f32x4)0.f;

  for (int k0 = 0; k0 < D_DIM; k0 += 64) {
    #pragma unroll
    for (int q = 0; q < 4; ++q) {
      int seg = q * 256 + tid;          // 0..1023
      int row = seg >> 3, k8 = seg & 7;
      uint4 va = *(const uint4*)(A + (size_t)(m0 + row) * D_DIM + k0 + k8 * 8);
      *(uint4*)(&As[row][k8 * 8]) = va;
      uint4 vb = *(const uint4*)(B + (size_t)(n0 + row) * D_DIM + k0 + k8 * 8);
      *(uint4*)(&Bs[row][k8 * 8]) = vb;
    }
    __syncthreads();
    #pragma unroll
    for (int kc = 0; kc < 2; ++kc) {
      int krow = kc * 32 + quad * 8;
      short8 a[4], b[4];
      #pragma unroll
      for (int mt = 0; mt < 4; ++mt)
        a[mt] = *(const short8*)(&As[wm * 64 + mt * 16 + l15][krow]);
      #pragma unroll
      for (int nt = 0; nt < 4; ++nt)
        b[nt] = *(const short8*)(&Bs[wn * 64 + nt * 16 + l15][krow]);
      #pragma unroll
      for (int mt = 0; mt < 4; ++mt)
        #pragma unroll
        for (int nt = 0; nt < 4; ++nt)
          acc[mt][nt] = __builtin_amdgcn_mfma_f32_16x16x32_bf16(a[mt], b[nt], acc[mt][nt], 0, 0, 0);
    }
    __syncthreads();
  }
  // epilogue: write bf16 into [t][n][4096]
  #pragma unroll
  for (int mt = 0; mt < 4; ++mt)
    #pragma unroll
    for (int nt = 0; nt < 4; ++nt)
      #pragma unroll
      for (int r = 0; r < 4; ++r) {
        int m = m0 + wm * 64 + mt * 16 + quad * 4 + r;
        int n = n0 + wn * 64 + nt * 16 + l15;
        int t = m & 511, nn = m >> 9;
        xz[(size_t)(t * 64 + nn) * FH + n] = f2bf(acc[mt][nt][r]);
      }
}

// ---------------------------------------------------------------------------
// Persistent cooperative LSTM scan.
// 128 blocks x 256 threads. Block owns 32 permuted gate-cols (8 h-cols).
// Wave w holds Wh B-fragments for K-slice [w*256,(w+1)*256) in registers.
//
// Cross-block exchange: agent-scope coherent accesses only (no per-step L2
// writeback/invalidate):
//   - h stores: relaxed agent-scope dword atomics (reach L3 coherence point),
//     drained with s_waitcnt vmcnt(0) before barrier arrival (round-1 proven).
//   - h loads:  relaxed agent-scope 64-bit atomic loads (global_load_dwordx2
//     with coherence bits), ALL 64 burst-issued into a statically-indexed
//     register array BEFORE any MFMA -> one L3 round trip, compiler-managed
//     waitcnts (no inline-asm destination registers; round-2's asm dwordx4
//     loads hit the rule-#18 regalloc-copy hazard and produced garbage).
//   - barrier:  distributed monotonic flags, one 128B line per block.
//     Arrival = fetch_add on the block's OWN line (proven RMW visibility,
//     zero cross-block contention); detection = threads 0..127 each poll one
//     block's flag. No shared hot line (round-1's single-counter serialized
//     128 RMWs at the L3 atomic unit).
// ---------------------------------------------------------------------------
__global__ __launch_bounds__(256, 1) void lstm_scan(
    const ushort* __restrict__ xz,    // [512][64][4096] bf16 (permuted cols)
    const ushort* __restrict__ WhT,   // [4096][1024] bf16 (permuted rows)
    const float*  __restrict__ bias,  // [4096] original order
    ushort* h0buf, ushort* h1buf,     // [64][1024] bf16 ping-pong
    float* __restrict__ out,          // [64][512][1024] fp32
    unsigned* arrive)                 // [128] flags, stride 32 dwords, pre-zeroed
{
  __shared__ float zpart[4 * 64 * 32];
  const int blk = blockIdx.x;     // 0..127
  const int tid = threadIdx.x;
  const int w = tid >> 6;         // wave = K-slice 0..3
  const int lane = tid & 63;
  const int quad = lane >> 4;
  const int l15 = lane & 15;

  // B fragments (Wh slice) -> registers: [nt][kc], K-offset = w*256+kc*32
  short8 bfrag[2][8];
  {
    const ushort* base = WhT + (size_t)(blk * 32) * D_DIM + w * 256;
    #pragma unroll
    for (int nt = 0; nt < 2; ++nt)
      #pragma unroll
      for (int kc = 0; kc < 8; ++kc)
        bfrag[nt][kc] = *(const short8*)(base + (size_t)(nt * 16 + l15) * D_DIM + kc * 32 + quad * 8);
  }

  // gate-phase assignment: thread -> (m = tid>>2, col-quad = tid&3)
  const int gm = tid >> 2;
  const int gq = tid & 3;
  float bb[8];
  #pragma unroll
  for (int j = 0; j < 8; ++j) {
    int c = gq * 8 + j;
    int gate = c & 3, hcl = c >> 2;
    bb[j] = bias[gate * 1024 + blk * 8 + hcl];
  }
  float cst[2] = {0.f, 0.f};

  const ushort* bufs[2] = {h0buf, h1buf};

  for (int t = 0; t < TT; ++t) {
    const ushort* rb = bufs[t & 1];
    ushort* wb = (ushort*)bufs[(t + 1) & 1];

    // prefetch xz for this thread's gate-phase cols (hidden under GEMM)
    uint4 xzv = *(const uint4*)(xz + (size_t)(t * 64 + gm) * FH + blk * 32 + gq * 8);

    // ---- burst-issue ALL h loads (coherent dwordx2), then all MFMAs ----
    ull areg[8][4][2];
    #pragma unroll
    for (int kc = 0; kc < 8; ++kc) {
      const ushort* ab = rb + w * 256 + kc * 32 + quad * 8;
      #pragma unroll
      for (int mt = 0; mt < 4; ++mt) {
        ull* ap = (ull*)(ab + (size_t)(mt * 16 + l15) * H_DIM);
        areg[kc][mt][0] = __hip_atomic_load(ap + 0, __ATOMIC_RELAXED, __HIP_MEMORY_SCOPE_AGENT);
        areg[kc][mt][1] = __hip_atomic_load(ap + 1, __ATOMIC_RELAXED, __HIP_MEMORY_SCOPE_AGENT);
      }
    }

    f32x4 acc[4][2];
    #pragma unroll
    for (int mt = 0; mt < 4; ++mt) { acc[mt][0] = (f32x4)0.f; acc[mt][1] = (f32x4)0.f; }

    #pragma unroll
    for (int kc = 0; kc < 8; ++kc) {
      #pragma unroll
      for (int mt = 0; mt < 4; ++mt) {
        union { ull u[2]; short8 s; } av;
        av.u[0] = areg[kc][mt][0]; av.u[1] = areg[kc][mt][1];
        acc[mt][0] = __builtin_amdgcn_mfma_f32_16x16x32_bf16(av.s, bfrag[0][kc], acc[mt][0], 0, 0, 0);
        acc[mt][1] = __builtin_amdgcn_mfma_f32_16x16x32_bf16(av.s, bfrag[1][kc], acc[mt][1], 0, 0, 0);
      }
    }

    // write K-partials to LDS: zpart[w][m][col]
    #pragma unroll
    for (int mt = 0; mt < 4; ++mt)
      #pragma unroll
      for (int nt = 0; nt < 2; ++nt)
        #pragma unroll
        for (int r = 0; r < 4; ++r) {
          int m = mt * 16 + quad * 4 + r;
          int col = nt * 16 + l15;
          zpart[(w * 64 + m) * 32 + col] = acc[mt][nt][r];
        }
    __syncthreads();

    // gate phase: 8 cols per thread = 2 h-cols x 4 gates
    float z[8];
    {
      const ushort* xp = (const ushort*)&xzv;
      #pragma unroll
      for (int j = 0; j < 8; ++j) z[j] = bb[j] + bf2f(xp[j]);
      #pragma unroll
      for (int wv = 0; wv < 4; ++wv) {
        const float4* pp = (const float4*)&zpart[(wv * 64 + gm) * 32 + gq * 8];
        float4 p0 = pp[0], p1 = pp[1];
        z[0] += p0.x; z[1] += p0.y; z[2] += p0.z; z[3] += p0.w;
        z[4] += p1.x; z[5] += p1.y; z[6] += p1.z; z[7] += p1.w;
      }
    }
    ushort hpack[2];
    float hout[2];
    #pragma unroll
    for (int p = 0; p < 2; ++p) {
      float ai = z[p * 4 + 0], af = z[p * 4 + 1], ao = z[p * 4 + 2], ag = z[p * 4 + 3];
      float ig = 1.f / (1.f + __expf(-ai));
      float fg = 1.f / (1.f + __expf(-af));
      float og = 1.f / (1.f + __expf(-ao));
      float gg = 2.f / (1.f + __expf(-2.f * ag)) - 1.f;   // tanh
      float c = fg * cst[p] + ig * gg;
      cst[p] = c;
      float th = 2.f / (1.f + __expf(-2.f * c)) - 1.f;    // tanh
      float h = og * th;
      hout[p] = h; hpack[p] = f2bf(h);
    }
    // h recurrence store: agent-scope write-through dword (reaches L3)
    unsigned hbits = (unsigned)hpack[0] | ((unsigned)hpack[1] << 16);
    __hip_atomic_store((unsigned*)(wb + (size_t)gm * H_DIM + blk * 8 + gq * 2), hbits,
                       __ATOMIC_RELAXED, __HIP_MEMORY_SCOPE_AGENT);
    // output store: plain (nobody reads it during the scan)
    float2 ho; ho.x = hout[0]; ho.y = hout[1];
    *(float2*)(out + ((size_t)gm * TT + t) * H_DIM + blk * 8 + gq * 2) = ho;

    // --- distributed-flag grid barrier ---
    // Drain this thread's coherent h stores, then block arrival = fetch_add
    // on the block's OWN flag line; threads 0..127 each poll one flag
    // (monotonic counters, no reset, no shared hot line).
    asm volatile("s_waitcnt vmcnt(0)" ::: "memory");
    __syncthreads();
    if (tid == 0)
      __hip_atomic_fetch_add(&arrive[blk * 32], 1u,
                             __ATOMIC_RELAXED, __HIP_MEMORY_SCOPE_AGENT);
    if (tid < SCAN_BLOCKS) {
      while (__hip_atomic_load(&arrive[tid * 32], __ATOMIC_RELAXED,
                               __HIP_MEMORY_SCOPE_AGENT) < (unsigned)(t + 1)) {}
    }
    __syncthreads();
  }
}

// ---------------------------------------------------------------------------
extern "C" void kernel_launch(void* const* d_in, const int* in_sizes, int n_in,
                              void* d_out, int out_size, void* d_ws, size_t ws_size,
                              hipStream_t stream) {
  const float* x  = (const float*)d_in[0];   // 64*512*1024
  const float* h0 = (const float*)d_in[1];   // 64*1024
  const float* Wx = (const float*)d_in[2];   // 1024*4096
  const float* Wh = (const float*)d_in[3];   // 1024*4096
  const float* b  = (const float*)d_in[4];   // 4096
  float* out = (float*)d_out;

  char* ws = (char*)d_ws;
  ushort* xz    = (ushort*)(ws + 0);                    // 268,435,456 B
  ushort* xb    = (ushort*)(ws + 268435456);            //  67,108,864 B (dead after gemm_xz)
  ushort* WxT   = (ushort*)(ws + 335544320);            //   8,388,608 B
  ushort* WhT   = (ushort*)(ws + 343932928);            //   8,388,608 B
  ushort* h0buf = (ushort*)(ws + 352321536);            //     131,072 B
  ushort* h1buf = (ushort*)(ws + 352452608);            //     131,072 B
  unsigned* arrive = (unsigned*)(ws + 268435456);       // 16 KB flags (aliases dead xb)

  transpose_perm<<<dim3(64, 16), 256, 0, stream>>>(Wx, WxT);
  transpose_perm<<<dim3(64, 16), 256, 0, stream>>>(Wh, WhT);
  cvt_x<<<32768, 256, 0, stream>>>(x, xb);
  cvt_h0<<<256, 256, 0, stream>>>(h0, h0buf);
  gemm_xz<<<8192, 256, 0, stream>>>(xb, WxT, xz);
  zero_flags<<<1, SCAN_BLOCKS, 0, stream>>>(arrive);   // after gemm_xz: xb dead

  void* args[] = {(void*)&xz, (void*)&WhT, (void*)&b, (void*)&h0buf, (void*)&h1buf,
                  (void*)&out, (void*)&arrive};
  hipLaunchCooperativeKernel((const void*)lstm_scan, dim3(SCAN_BLOCKS), dim3(256), args, 0, stream);
}

// Round 4
// 3984.714 us; speedup vs baseline: 3.0530x; 1.4700x over previous
//
#include <hip/hip_runtime.h>

typedef __attribute__((ext_vector_type(8))) short short8;
typedef __attribute__((ext_vector_type(4))) float f32x4;
typedef unsigned long long ull;

#define D_DIM 1024
#define H_DIM 1024
#define FH 4096
#define NB 64
#define TT 512
#define MROWS (NB * TT)   // 32768
#define SCAN_BLOCKS 128

__device__ __forceinline__ ushort f2bf(float f) {
  union { float f; unsigned u; } v; v.f = f;
  unsigned u = v.u;
  return (ushort)((u + 0x7FFFu + ((u >> 16) & 1u)) >> 16);
}
__device__ __forceinline__ float bf2f(ushort h) {
  union { unsigned u; float f; } v; v.u = ((unsigned)h) << 16;
  return v.f;
}

// ---------------------------------------------------------------------------
// Transpose + fp32->bf16 convert + gate-interleaved column permutation.
// W: [1024][4096] row-major.  WT row r = b*32 + hc_local*4 + gate  maps to
// original column  oc = gate*1024 + b*8 + hc_local.  WT: [4096][1024] bf16.
// ---------------------------------------------------------------------------
__global__ void transpose_perm(const float* __restrict__ W, ushort* __restrict__ WT) {
  __shared__ ushort tile[64][65];
  int ocTile = blockIdx.x * 64;
  int kTile  = blockIdx.y * 64;
  int tx = threadIdx.x & 63, ty = threadIdx.x >> 6;
  #pragma unroll
  for (int i = 0; i < 16; ++i) {
    int r = ty + i * 4;  // k offset
    float v = W[(size_t)(kTile + r) * FH + ocTile + tx];
    tile[r][tx] = f2bf(v);
  }
  __syncthreads();
  #pragma unroll
  for (int i = 0; i < 16; ++i) {
    int c = ty + i * 4;              // column offset within tile
    int oc = ocTile + c;
    int gate = oc >> 10, rem = oc & 1023;
    int b = rem >> 3, hcl = rem & 7;
    int r_out = b * 32 + hcl * 4 + gate;
    WT[(size_t)r_out * D_DIM + kTile + tx] = tile[tx][c];
  }
}

// x fp32 -> bf16, one float4 per thread. grid 32768, block 256.
__global__ void cvt_x(const float* __restrict__ x, ushort* __restrict__ xb) {
  size_t i = (size_t)blockIdx.x * blockDim.x + threadIdx.x;
  const float4* x4 = (const float4*)x;
  float4 v = x4[i];
  ushort4 o; o.x = f2bf(v.x); o.y = f2bf(v.y); o.z = f2bf(v.z); o.w = f2bf(v.w);
  ((ushort4*)xb)[i] = o;
}

// h0 fp32 -> bf16 into h_buf0. grid 256, block 256.
__global__ void cvt_h0(const float* __restrict__ h0, ushort* __restrict__ hb) {
  int i = blockIdx.x * blockDim.x + threadIdx.x;
  hb[i] = f2bf(h0[i]);
}

// zero the barrier arrival flags (runs after gemm_xz, which reads this region).
__global__ void zero_flags(unsigned* f) { f[threadIdx.x * 32] = 0u; }

// ---------------------------------------------------------------------------
// xz GEMM: A = x_bf16 [32768][1024], B = WxT_perm [4096][1024] (both K-contig)
// 128x128 tile, BK=64, 256 threads (4 waves as 2x2 of 64x64).
// ---------------------------------------------------------------------------
__global__ __launch_bounds__(256) void gemm_xz(const ushort* __restrict__ A,
                                               const ushort* __restrict__ B,
                                               ushort* __restrict__ xz) {
  __shared__ ushort As[128][72];
  __shared__ ushort Bs[128][72];
  int bid = blockIdx.x;
  int nb = bid & 31, mb = bid >> 5;
  int m0 = mb * 128, n0 = nb * 128;
  int tid = threadIdx.x;
  int lane = tid & 63, w = tid >> 6;
  int wm = w >> 1, wn = w & 1;
  int quad = lane >> 4, l15 = lane & 15;

  f32x4 acc[4][4];
  #pragma unroll
  for (int i = 0; i < 4; ++i)
    #pragma unroll
    for (int j = 0; j < 4; ++j) acc[i][j] = (f32x4)0.f;

  for (int k0 = 0; k0 < D_DIM; k0 += 64) {
    #pragma unroll
    for (int q = 0; q < 4; ++q) {
      int seg = q * 256 + tid;          // 0..1023
      int row = seg >> 3, k8 = seg & 7;
      uint4 va = *(const uint4*)(A + (size_t)(m0 + row) * D_DIM + k0 + k8 * 8);
      *(uint4*)(&As[row][k8 * 8]) = va;
      uint4 vb = *(const uint4*)(B + (size_t)(n0 + row) * D_DIM + k0 + k8 * 8);
      *(uint4*)(&Bs[row][k8 * 8]) = vb;
    }
    __syncthreads();
    #pragma unroll
    for (int kc = 0; kc < 2; ++kc) {
      int krow = kc * 32 + quad * 8;
      short8 a[4], b[4];
      #pragma unroll
      for (int mt = 0; mt < 4; ++mt)
        a[mt] = *(const short8*)(&As[wm * 64 + mt * 16 + l15][krow]);
      #pragma unroll
      for (int nt = 0; nt < 4; ++nt)
        b[nt] = *(const short8*)(&Bs[wn * 64 + nt * 16 + l15][krow]);
      #pragma unroll
      for (int mt = 0; mt < 4; ++mt)
        #pragma unroll
        for (int nt = 0; nt < 4; ++nt)
          acc[mt][nt] = __builtin_amdgcn_mfma_f32_16x16x32_bf16(a[mt], b[nt], acc[mt][nt], 0, 0, 0);
    }
    __syncthreads();
  }
  // epilogue: write bf16 into [t][n][4096]
  #pragma unroll
  for (int mt = 0; mt < 4; ++mt)
    #pragma unroll
    for (int nt = 0; nt < 4; ++nt)
      #pragma unroll
      for (int r = 0; r < 4; ++r) {
        int m = m0 + wm * 64 + mt * 16 + quad * 4 + r;
        int n = n0 + wn * 64 + nt * 16 + l15;
        int t = m & 511, nn = m >> 9;
        xz[(size_t)(t * 64 + nn) * FH + n] = f2bf(acc[mt][nt][r]);
      }
}

// ---------------------------------------------------------------------------
// Persistent cooperative LSTM scan — re-tiled for load-latency.
// 128 blocks = 2 row-groups (32 batch rows) x 64 col-groups (64 permuted
// gate-cols = 16 h-cols). 256 threads = 4 waves; wave w owns K-slice
// [w*256,(w+1)*256).  Per wave: M=32 (mt 0..1), N=64 (nt 0..3), 64 MFMAs.
//
// Why this shape: round-3 counters showed VGPR stuck at 84 -> the compiler
// chunked the 64-load h burst into serialized L3 round trips. Here each
// thread needs only 32 x 8B coherent loads from TWO row-base pointers
// (64-VGPR landing zone) -> the whole burst stays in flight, ~1 round trip.
// B (Wh) fragments stay register-resident: bfrag[4][8] = 128 VGPRs.
//
// Cross-block exchange mechanisms unchanged from round 3 (all proven):
//   h stores = relaxed agent-scope dword atomics; h loads = relaxed
//   agent-scope ull atomic loads; distributed per-block flag barrier
//   (fetch_add own line, 128 parallel pollers); vmcnt(0) drain before arrive.
// ---------------------------------------------------------------------------
__global__ __launch_bounds__(256, 1) void lstm_scan(
    const ushort* __restrict__ xz,    // [512][64][4096] bf16 (permuted cols)
    const ushort* __restrict__ WhT,   // [4096][1024] bf16 (permuted rows)
    const float*  __restrict__ bias,  // [4096] original order
    ushort* h0buf, ushort* h1buf,     // [64][1024] bf16 ping-pong
    float* __restrict__ out,          // [64][512][1024] fp32
    unsigned* arrive)                 // [128] flags, stride 32 dwords, pre-zeroed
{
  __shared__ float zpart[4 * 32 * 68];  // [w][m 0..31][col 0..63], stride 68 (pad 4)
  const int blk = blockIdx.x;     // 0..127
  const int tid = threadIdx.x;
  const int w = tid >> 6;         // wave = K-slice 0..3
  const int lane = tid & 63;
  const int quad = lane >> 4;
  const int l15 = lane & 15;

  const int mg = blk >> 6;        // 0..1   batch-row group (32 rows)
  const int cg = blk & 63;        // 0..63  col group (64 permuted cols)
  const int m0 = mg * 32;

  // B fragments (Wh slice) -> registers: bfrag[nt][kc], K-off = w*256+kc*32
  short8 bfrag[4][8];
  {
    const ushort* base = WhT + (size_t)(cg * 64) * D_DIM + w * 256;
    #pragma unroll
    for (int nt = 0; nt < 4; ++nt)
      #pragma unroll
      for (int kc = 0; kc < 8; ++kc)
        bfrag[nt][kc] = *(const short8*)(base + (size_t)(nt * 16 + l15) * D_DIM + kc * 32 + quad * 8);
  }

  // gate-phase assignment: thread -> (row gm 0..31, col-octet gq 0..7)
  const int gm = tid >> 3;
  const int gq = tid & 7;
  const int hc2 = (gq >> 2) * 8 + (gq & 3) * 2;   // local h-col pair base (0..15)
  float bb[8];
  #pragma unroll
  for (int j = 0; j < 8; ++j)
    bb[j] = bias[(j & 3) * 1024 + cg * 16 + hc2 + (j >> 2)];
  float cst[2] = {0.f, 0.f};

  const ushort* bufs[2] = {h0buf, h1buf};

  for (int t = 0; t < TT; ++t) {
    const ushort* rb = bufs[t & 1];
    ushort* wb = (ushort*)bufs[(t + 1) & 1];

    // prefetch xz for this thread's gate-phase cols (hidden under h loads)
    uint4 xzv = *(const uint4*)(xz + (size_t)(t * 64 + m0 + gm) * FH + cg * 64 + gq * 8);

    // ---- burst-issue ALL h loads: 32 x 8B from 2 row bases + immediates ----
    ull areg[2][8][2];
    {
      const ushort* r0 = rb + (size_t)(m0 + l15) * H_DIM + w * 256 + quad * 8;
      const ushort* r1 = r0 + 16 * H_DIM;
      #pragma unroll
      for (int kc = 0; kc < 8; ++kc) {
        areg[0][kc][0] = __hip_atomic_load((const ull*)(r0 + kc * 32),     __ATOMIC_RELAXED, __HIP_MEMORY_SCOPE_AGENT);
        areg[0][kc][1] = __hip_atomic_load((const ull*)(r0 + kc * 32 + 4), __ATOMIC_RELAXED, __HIP_MEMORY_SCOPE_AGENT);
        areg[1][kc][0] = __hip_atomic_load((const ull*)(r1 + kc * 32),     __ATOMIC_RELAXED, __HIP_MEMORY_SCOPE_AGENT);
        areg[1][kc][1] = __hip_atomic_load((const ull*)(r1 + kc * 32 + 4), __ATOMIC_RELAXED, __HIP_MEMORY_SCOPE_AGENT);
      }
    }

    f32x4 acc[2][4];
    #pragma unroll
    for (int mt = 0; mt < 2; ++mt)
      #pragma unroll
      for (int nt = 0; nt < 4; ++nt) acc[mt][nt] = (f32x4)0.f;

    #pragma unroll
    for (int kc = 0; kc < 8; ++kc) {
      #pragma unroll
      for (int mt = 0; mt < 2; ++mt) {
        union { ull u[2]; short8 s; } av;
        av.u[0] = areg[mt][kc][0]; av.u[1] = areg[mt][kc][1];
        #pragma unroll
        for (int nt = 0; nt < 4; ++nt)
          acc[mt][nt] = __builtin_amdgcn_mfma_f32_16x16x32_bf16(av.s, bfrag[nt][kc], acc[mt][nt], 0, 0, 0);
      }
    }

    // write K-partials to LDS: zpart[w][m][col], stride 68 -> 2-way (free)
    #pragma unroll
    for (int mt = 0; mt < 2; ++mt)
      #pragma unroll
      for (int nt = 0; nt < 4; ++nt)
        #pragma unroll
        for (int r = 0; r < 4; ++r) {
          int m = mt * 16 + quad * 4 + r;
          int col = nt * 16 + l15;
          zpart[(w * 32 + m) * 68 + col] = acc[mt][nt][r];
        }
    __syncthreads();

    // gate phase: 8 cols per thread = 2 h-cols x 4 gates
    float z[8];
    {
      const ushort* xp = (const ushort*)&xzv;
      #pragma unroll
      for (int j = 0; j < 8; ++j) z[j] = bb[j] + bf2f(xp[j]);
      #pragma unroll
      for (int wv = 0; wv < 4; ++wv) {
        const float4* pp = (const float4*)&zpart[(wv * 32 + gm) * 68 + gq * 8];
        float4 p0 = pp[0], p1 = pp[1];
        z[0] += p0.x; z[1] += p0.y; z[2] += p0.z; z[3] += p0.w;
        z[4] += p1.x; z[5] += p1.y; z[6] += p1.z; z[7] += p1.w;
      }
    }
    ushort hpack[2];
    float hout[2];
    #pragma unroll
    for (int p = 0; p < 2; ++p) {
      float ai = z[p * 4 + 0], af = z[p * 4 + 1], ao = z[p * 4 + 2], ag = z[p * 4 + 3];
      float ig = 1.f / (1.f + __expf(-ai));
      float fg = 1.f / (1.f + __expf(-af));
      float og = 1.f / (1.f + __expf(-ao));
      float gg = 2.f / (1.f + __expf(-2.f * ag)) - 1.f;   // tanh
      float c = fg * cst[p] + ig * gg;
      cst[p] = c;
      float th = 2.f / (1.f + __expf(-2.f * c)) - 1.f;    // tanh
      float h = og * th;
      hout[p] = h; hpack[p] = f2bf(h);
    }
    // h recurrence store: agent-scope write-through dword (reaches L3)
    unsigned hbits = (unsigned)hpack[0] | ((unsigned)hpack[1] << 16);
    __hip_atomic_store((unsigned*)(wb + (size_t)(m0 + gm) * H_DIM + cg * 16 + hc2), hbits,
                       __ATOMIC_RELAXED, __HIP_MEMORY_SCOPE_AGENT);
    // output store: plain (nobody reads it during the scan)
    float2 ho; ho.x = hout[0]; ho.y = hout[1];
    *(float2*)(out + ((size_t)(m0 + gm) * TT + t) * H_DIM + cg * 16 + hc2) = ho;

    // --- distributed-flag grid barrier (round-3 proven) ---
    asm volatile("s_waitcnt vmcnt(0)" ::: "memory");
    __syncthreads();
    if (tid == 0)
      __hip_atomic_fetch_add(&arrive[blk * 32], 1u,
                             __ATOMIC_RELAXED, __HIP_MEMORY_SCOPE_AGENT);
    if (tid < SCAN_BLOCKS) {
      while (__hip_atomic_load(&arrive[tid * 32], __ATOMIC_RELAXED,
                               __HIP_MEMORY_SCOPE_AGENT) < (unsigned)(t + 1)) {}
    }
    __syncthreads();
  }
}

// ---------------------------------------------------------------------------
extern "C" void kernel_launch(void* const* d_in, const int* in_sizes, int n_in,
                              void* d_out, int out_size, void* d_ws, size_t ws_size,
                              hipStream_t stream) {
  const float* x  = (const float*)d_in[0];   // 64*512*1024
  const float* h0 = (const float*)d_in[1];   // 64*1024
  const float* Wx = (const float*)d_in[2];   // 1024*4096
  const float* Wh = (const float*)d_in[3];   // 1024*4096
  const float* b  = (const float*)d_in[4];   // 4096
  float* out = (float*)d_out;

  char* ws = (char*)d_ws;
  ushort* xz    = (ushort*)(ws + 0);                    // 268,435,456 B
  ushort* xb    = (ushort*)(ws + 268435456);            //  67,108,864 B (dead after gemm_xz)
  ushort* WxT   = (ushort*)(ws + 335544320);            //   8,388,608 B
  ushort* WhT   = (ushort*)(ws + 343932928);            //   8,388,608 B
  ushort* h0buf = (ushort*)(ws + 352321536);            //     131,072 B
  ushort* h1buf = (ushort*)(ws + 352452608);            //     131,072 B
  unsigned* arrive = (unsigned*)(ws + 268435456);       // 16 KB flags (aliases dead xb)

  transpose_perm<<<dim3(64, 16), 256, 0, stream>>>(Wx, WxT);
  transpose_perm<<<dim3(64, 16), 256, 0, stream>>>(Wh, WhT);
  cvt_x<<<32768, 256, 0, stream>>>(x, xb);
  cvt_h0<<<256, 256, 0, stream>>>(h0, h0buf);
  gemm_xz<<<8192, 256, 0, stream>>>(xb, WxT, xz);
  zero_flags<<<1, SCAN_BLOCKS, 0, stream>>>(arrive);   // after gemm_xz: xb dead

  void* args[] = {(void*)&xz, (void*)&WhT, (void*)&b, (void*)&h0buf, (void*)&h1buf,
                  (void*)&out, (void*)&arrive};
  hipLaunchCooperativeKernel((const void*)lstm_scan, dim3(SCAN_BLOCKS), dim3(256), args, 0, stream);
}

// Round 5
// 3728.625 us; speedup vs baseline: 3.2627x; 1.0687x over previous
//
#include <hip/hip_runtime.h>

typedef __attribute__((ext_vector_type(8))) short short8;
typedef __attribute__((ext_vector_type(4))) float f32x4;
typedef unsigned long long ull;

#define D_DIM 1024
#define H_DIM 1024
#define FH 4096
#define NB 64
#define TT 512
#define MROWS (NB * TT)   // 32768
#define SCAN_BLOCKS 256

__device__ __forceinline__ ushort f2bf(float f) {
  union { float f; unsigned u; } v; v.f = f;
  unsigned u = v.u;
  return (ushort)((u + 0x7FFFu + ((u >> 16) & 1u)) >> 16);
}
__device__ __forceinline__ float bf2f(ushort h) {
  union { unsigned u; float f; } v; v.u = ((unsigned)h) << 16;
  return v.f;
}

// ---------------------------------------------------------------------------
// Transpose + fp32->bf16 convert + gate-interleaved column permutation.
// W: [1024][4096] row-major.  WT row r = b*32 + hc_local*4 + gate  maps to
// original column  oc = gate*1024 + b*8 + hc_local.  WT: [4096][1024] bf16.
// ---------------------------------------------------------------------------
__global__ void transpose_perm(const float* __restrict__ W, ushort* __restrict__ WT) {
  __shared__ ushort tile[64][65];
  int ocTile = blockIdx.x * 64;
  int kTile  = blockIdx.y * 64;
  int tx = threadIdx.x & 63, ty = threadIdx.x >> 6;
  #pragma unroll
  for (int i = 0; i < 16; ++i) {
    int r = ty + i * 4;  // k offset
    float v = W[(size_t)(kTile + r) * FH + ocTile + tx];
    tile[r][tx] = f2bf(v);
  }
  __syncthreads();
  #pragma unroll
  for (int i = 0; i < 16; ++i) {
    int c = ty + i * 4;              // column offset within tile
    int oc = ocTile + c;
    int gate = oc >> 10, rem = oc & 1023;
    int b = rem >> 3, hcl = rem & 7;
    int r_out = b * 32 + hcl * 4 + gate;
    WT[(size_t)r_out * D_DIM + kTile + tx] = tile[tx][c];
  }
}

// x fp32 -> bf16, one float4 per thread. grid 32768, block 256.
__global__ void cvt_x(const float* __restrict__ x, ushort* __restrict__ xb) {
  size_t i = (size_t)blockIdx.x * blockDim.x + threadIdx.x;
  const float4* x4 = (const float4*)x;
  float4 v = x4[i];
  ushort4 o; o.x = f2bf(v.x); o.y = f2bf(v.y); o.z = f2bf(v.z); o.w = f2bf(v.w);
  ((ushort4*)xb)[i] = o;
}

// h0 fp32 -> bf16 into h_buf0. grid 256, block 256.
__global__ void cvt_h0(const float* __restrict__ h0, ushort* __restrict__ hb) {
  int i = blockIdx.x * blockDim.x + threadIdx.x;
  hb[i] = f2bf(h0[i]);
}

// zero the barrier arrival flags (one 128B line per block).
__global__ void zero_flags(unsigned* f) { f[threadIdx.x * 32] = 0u; }

// ---------------------------------------------------------------------------
// xz GEMM: A = x_bf16 [32768][1024], B = WxT_perm [4096][1024] (both K-contig)
// 128x128 tile, BK=64, 256 threads (4 waves as 2x2 of 64x64).
// ---------------------------------------------------------------------------
__global__ __launch_bounds__(256) void gemm_xz(const ushort* __restrict__ A,
                                               const ushort* __restrict__ B,
                                               ushort* __restrict__ xz) {
  __shared__ ushort As[128][72];
  __shared__ ushort Bs[128][72];
  int bid = blockIdx.x;
  int nb = bid & 31, mb = bid >> 5;
  int m0 = mb * 128, n0 = nb * 128;
  int tid = threadIdx.x;
  int lane = tid & 63, w = tid >> 6;
  int wm = w >> 1, wn = w & 1;
  int quad = lane >> 4, l15 = lane & 15;

  f32x4 acc[4][4];
  #pragma unroll
  for (int i = 0; i < 4; ++i)
    #pragma unroll
    for (int j = 0; j < 4; ++j) acc[i][j] = (f32x4)0.f;

  for (int k0 = 0; k0 < D_DIM; k0 += 64) {
    #pragma unroll
    for (int q = 0; q < 4; ++q) {
      int seg = q * 256 + tid;          // 0..1023
      int row = seg >> 3, k8 = seg & 7;
      uint4 va = *(const uint4*)(A + (size_t)(m0 + row) * D_DIM + k0 + k8 * 8);
      *(uint4*)(&As[row][k8 * 8]) = va;
      uint4 vb = *(const uint4*)(B + (size_t)(n0 + row) * D_DIM + k0 + k8 * 8);
      *(uint4*)(&Bs[row][k8 * 8]) = vb;
    }
    __syncthreads();
    #pragma unroll
    for (int kc = 0; kc < 2; ++kc) {
      int krow = kc * 32 + quad * 8;
      short8 a[4], b[4];
      #pragma unroll
      for (int mt = 0; mt < 4; ++mt)
        a[mt] = *(const short8*)(&As[wm * 64 + mt * 16 + l15][krow]);
      #pragma unroll
      for (int nt = 0; nt < 4; ++nt)
        b[nt] = *(const short8*)(&Bs[wn * 64 + nt * 16 + l15][krow]);
      #pragma unroll
      for (int mt = 0; mt < 4; ++mt)
        #pragma unroll
        for (int nt = 0; nt < 4; ++nt)
          acc[mt][nt] = __builtin_amdgcn_mfma_f32_16x16x32_bf16(a[mt], b[nt], acc[mt][nt], 0, 0, 0);
    }
    __syncthreads();
  }
  // epilogue: write bf16 into [t][n][4096]
  #pragma unroll
  for (int mt = 0; mt < 4; ++mt)
    #pragma unroll
    for (int nt = 0; nt < 4; ++nt)
      #pragma unroll
      for (int r = 0; r < 4; ++r) {
        int m = m0 + wm * 64 + mt * 16 + quad * 4 + r;
        int n = n0 + wn * 64 + nt * 16 + l15;
        int t = m & 511, nn = m >> 9;
        xz[(size_t)(t * 64 + nn) * FH + n] = f2bf(acc[mt][nt][r]);
      }
}

// ---------------------------------------------------------------------------
// Persistent cooperative LSTM scan — full-GPU, Wh-in-LDS.
// 256 blocks = 4 row-groups (16 batch rows) x 64 col-groups (64 permuted
// gate-cols = 16 h-cols). 256 threads = 4 waves; wave w owns K-slice
// [w*256,(w+1)*256).  Per wave: M=16, N=64 -> 32 MFMAs/step.
//
// Round-4 lesson: VGPR_Count=108 proved the compiler would NOT keep
// bfrag[4][8] (128 VGPRs) resident -> Wh was re-fetched from L2 every step
// (dependent-load chain on the critical path). Fix: stage the block's Wh
// slice (64 cols x 1024 K bf16 = 128 KiB) into LDS ONCE before the t-loop,
// XOR-swizzled (byte ^= (row&7)<<4) so the per-(nt,kc) column-slice
// ds_read_b128 is ~2-way (free) instead of 16-way conflicted.
// Per-thread register demand drops to ~100 -> the 16-load h burst
// (one base pointer + immediate offsets) genuinely stays in flight.
//
// Cross-block exchange mechanisms byte-identical to rounds 3/4 (proven):
//   h stores = relaxed agent-scope dword atomics; h loads = relaxed
//   agent-scope ull atomic loads; distributed per-block flag barrier
//   (fetch_add own line, parallel pollers); vmcnt(0) drain before arrive.
// ---------------------------------------------------------------------------
__global__ __launch_bounds__(256, 1) void lstm_scan(
    const ushort* __restrict__ xz,    // [512][64][4096] bf16 (permuted cols)
    const ushort* __restrict__ WhT,   // [4096][1024] bf16 (permuted rows)
    const float*  __restrict__ bias,  // [4096] original order
    ushort* h0buf, ushort* h1buf,     // [64][1024] bf16 ping-pong
    float* __restrict__ out,          // [64][512][1024] fp32
    unsigned* arrive)                 // [256] flags, stride 32 dwords, pre-zeroed
{
  __shared__ ushort whlds[64 * 1024];       // 128 KiB, XOR-swizzled rows
  __shared__ float zpart[4 * 16 * 68];      // [w][m 0..15][col 0..63], stride 68

  const int blk = blockIdx.x;     // 0..255
  const int tid = threadIdx.x;
  const int w = tid >> 6;         // wave = K-slice 0..3
  const int lane = tid & 63;
  const int quad = lane >> 4;
  const int l15 = lane & 15;

  const int mg = blk >> 6;        // 0..3   batch-row group (16 rows)
  const int cg = blk & 63;        // 0..63  col group (64 permuted cols)
  const int m0 = mg * 16;

  // ---- stage Wh slice into LDS once (XOR-swizzled 16B granules) ----
  {
    const ushort* src = WhT + (size_t)(cg * 64) * D_DIM;
    #pragma unroll
    for (int it = 0; it < 32; ++it) {
      int idx = it * 256 + tid;           // 0..8191 chunks of 16B
      int row = idx >> 7;                 // 0..63 (col index)
      int slot = idx & 127;               // 16B slot within the 2048B row
      uint4 v = *(const uint4*)(src + (size_t)row * D_DIM + slot * 8);
      int byteoff = row * 2048 + ((slot * 16) ^ ((row & 7) << 4));
      *(uint4*)((char*)whlds + byteoff) = v;
    }
  }

  // gate-phase assignment (threads 0..127): row gm 0..15, col-octet gq 0..7
  const int gm = tid >> 3;        // valid for tid < 128
  const int gq = tid & 7;
  const int hc2 = (gq >> 2) * 8 + (gq & 3) * 2;   // local h-col pair base
  float bb[8];
  #pragma unroll
  for (int j = 0; j < 8; ++j)
    bb[j] = bias[(j & 3) * 1024 + cg * 16 + hc2 + (j >> 2)];
  float cst[2] = {0.f, 0.f};

  const ushort* bufs[2] = {h0buf, h1buf};
  __syncthreads();   // whlds ready

  for (int t = 0; t < TT; ++t) {
    const ushort* rb = bufs[t & 1];
    ushort* wb = (ushort*)bufs[(t + 1) & 1];

    // prefetch xz for this thread's gate-phase cols (hidden under h loads)
    uint4 xzv;
    if (tid < 128)
      xzv = *(const uint4*)(xz + (size_t)(t * 64 + m0 + gm) * FH + cg * 64 + gq * 8);

    // ---- burst-issue ALL h loads: 16 x 8B from ONE row base + immediates ----
    ull areg[8][2];
    {
      const ushort* r0 = rb + (size_t)(m0 + l15) * H_DIM + w * 256 + quad * 8;
      #pragma unroll
      for (int kc = 0; kc < 8; ++kc) {
        areg[kc][0] = __hip_atomic_load((const ull*)(r0 + kc * 32),     __ATOMIC_RELAXED, __HIP_MEMORY_SCOPE_AGENT);
        areg[kc][1] = __hip_atomic_load((const ull*)(r0 + kc * 32 + 4), __ATOMIC_RELAXED, __HIP_MEMORY_SCOPE_AGENT);
      }
    }

    f32x4 acc[4];
    #pragma unroll
    for (int nt = 0; nt < 4; ++nt) acc[nt] = (f32x4)0.f;

    #pragma unroll
    for (int kc = 0; kc < 8; ++kc) {
      union { ull u[2]; short8 s; } av;
      av.u[0] = areg[kc][0]; av.u[1] = areg[kc][1];
      const int koff = (w * 512 + kc * 64 + quad * 16) ^ ((l15 & 7) << 4);
      #pragma unroll
      for (int nt = 0; nt < 4; ++nt) {
        short8 bf = *(const short8*)((const char*)whlds + (nt * 16 + l15) * 2048 + koff);
        acc[nt] = __builtin_amdgcn_mfma_f32_16x16x32_bf16(av.s, bf, acc[nt], 0, 0, 0);
      }
    }

    // write K-partials to LDS: zpart[w][m][col], stride 68 -> 2-way (free)
    #pragma unroll
    for (int nt = 0; nt < 4; ++nt)
      #pragma unroll
      for (int r = 0; r < 4; ++r) {
        int m = quad * 4 + r;
        zpart[(w * 16 + m) * 68 + nt * 16 + l15] = acc[nt][r];
      }
    __syncthreads();

    // gate phase on threads 0..127: 8 cols = 2 h-cols x 4 gates
    ushort hpack[2];
    float hout[2];
    if (tid < 128) {
      float z[8];
      const ushort* xp = (const ushort*)&xzv;
      #pragma unroll
      for (int j = 0; j < 8; ++j) z[j] = bb[j] + bf2f(xp[j]);
      #pragma unroll
      for (int wv = 0; wv < 4; ++wv) {
        const float4* pp = (const float4*)&zpart[(wv * 16 + gm) * 68 + gq * 8];
        float4 p0 = pp[0], p1 = pp[1];
        z[0] += p0.x; z[1] += p0.y; z[2] += p0.z; z[3] += p0.w;
        z[4] += p1.x; z[5] += p1.y; z[6] += p1.z; z[7] += p1.w;
      }
      #pragma unroll
      for (int p = 0; p < 2; ++p) {
        float ai = z[p * 4 + 0], af = z[p * 4 + 1], ao = z[p * 4 + 2], ag = z[p * 4 + 3];
        float ig = 1.f / (1.f + __expf(-ai));
        float fg = 1.f / (1.f + __expf(-af));
        float og = 1.f / (1.f + __expf(-ao));
        float gg = 2.f / (1.f + __expf(-2.f * ag)) - 1.f;   // tanh
        float c = fg * cst[p] + ig * gg;
        cst[p] = c;
        float th = 2.f / (1.f + __expf(-2.f * c)) - 1.f;    // tanh
        float h = og * th;
        hout[p] = h; hpack[p] = f2bf(h);
      }
      // h recurrence store: agent-scope write-through dword (reaches L3)
      unsigned hbits = (unsigned)hpack[0] | ((unsigned)hpack[1] << 16);
      __hip_atomic_store((unsigned*)(wb + (size_t)(m0 + gm) * H_DIM + cg * 16 + hc2), hbits,
                         __ATOMIC_RELAXED, __HIP_MEMORY_SCOPE_AGENT);
      // output store: plain (nobody reads it during the scan)
      float2 ho; ho.x = hout[0]; ho.y = hout[1];
      *(float2*)(out + ((size_t)(m0 + gm) * TT + t) * H_DIM + cg * 16 + hc2) = ho;
    }

    // --- distributed-flag grid barrier (rounds 3/4 proven) ---
    asm volatile("s_waitcnt vmcnt(0)" ::: "memory");
    __syncthreads();
    if (tid == 0)
      __hip_atomic_fetch_add(&arrive[blk * 32], 1u,
                             __ATOMIC_RELAXED, __HIP_MEMORY_SCOPE_AGENT);
    {
      while (__hip_atomic_load(&arrive[tid * 32], __ATOMIC_RELAXED,
                               __HIP_MEMORY_SCOPE_AGENT) < (unsigned)(t + 1)) {}
    }
    __syncthreads();
  }
}

// ---------------------------------------------------------------------------
extern "C" void kernel_launch(void* const* d_in, const int* in_sizes, int n_in,
                              void* d_out, int out_size, void* d_ws, size_t ws_size,
                              hipStream_t stream) {
  const float* x  = (const float*)d_in[0];   // 64*512*1024
  const float* h0 = (const float*)d_in[1];   // 64*1024
  const float* Wx = (const float*)d_in[2];   // 1024*4096
  const float* Wh = (const float*)d_in[3];   // 1024*4096
  const float* b  = (const float*)d_in[4];   // 4096
  float* out = (float*)d_out;

  char* ws = (char*)d_ws;
  ushort* xz    = (ushort*)(ws + 0);                    // 268,435,456 B
  ushort* xb    = (ushort*)(ws + 268435456);            //  67,108,864 B (dead after gemm_xz)
  ushort* WxT   = (ushort*)(ws + 335544320);            //   8,388,608 B
  ushort* WhT   = (ushort*)(ws + 343932928);            //   8,388,608 B
  ushort* h0buf = (ushort*)(ws + 352321536);            //     131,072 B
  ushort* h1buf = (ushort*)(ws + 352452608);            //     131,072 B
  unsigned* arrive = (unsigned*)(ws + 268435456);       // 32 KB flags (aliases dead xb)

  transpose_perm<<<dim3(64, 16), 256, 0, stream>>>(Wx, WxT);
  transpose_perm<<<dim3(64, 16), 256, 0, stream>>>(Wh, WhT);
  cvt_x<<<32768, 256, 0, stream>>>(x, xb);
  cvt_h0<<<256, 256, 0, stream>>>(h0, h0buf);
  gemm_xz<<<8192, 256, 0, stream>>>(xb, WxT, xz);
  zero_flags<<<1, SCAN_BLOCKS, 0, stream>>>(arrive);   // after gemm_xz: xb dead

  void* args[] = {(void*)&xz, (void*)&WhT, (void*)&b, (void*)&h0buf, (void*)&h1buf,
                  (void*)&out, (void*)&arrive};
  hipLaunchCooperativeKernel((const void*)lstm_scan, dim3(SCAN_BLOCKS), dim3(256), args, 0, stream);
}

// Round 6
// 2974.810 us; speedup vs baseline: 4.0895x; 1.2534x over previous
//
#include <hip/hip_runtime.h>

typedef __attribute__((ext_vector_type(8))) short short8;
typedef __attribute__((ext_vector_type(4))) float f32x4;
typedef unsigned long long ull;

#define D_DIM 1024
#define H_DIM 1024
#define FH 4096
#define NB 64
#define TT 512
#define MROWS (NB * TT)   // 32768
#define SCAN_BLOCKS 256

__device__ __forceinline__ ushort f2bf(float f) {
  union { float f; unsigned u; } v; v.f = f;
  unsigned u = v.u;
  return (ushort)((u + 0x7FFFu + ((u >> 16) & 1u)) >> 16);
}
__device__ __forceinline__ float bf2f(ushort h) {
  union { unsigned u; float f; } v; v.u = ((unsigned)h) << 16;
  return v.f;
}

// ---------------------------------------------------------------------------
// Transpose + fp32->bf16 convert + gate-interleaved column permutation.
// W: [1024][4096] row-major.  WT row r = b*32 + hc_local*4 + gate  maps to
// original column  oc = gate*1024 + b*8 + hc_local.  WT: [4096][1024] bf16.
// ---------------------------------------------------------------------------
__global__ void transpose_perm(const float* __restrict__ W, ushort* __restrict__ WT) {
  __shared__ ushort tile[64][65];
  int ocTile = blockIdx.x * 64;
  int kTile  = blockIdx.y * 64;
  int tx = threadIdx.x & 63, ty = threadIdx.x >> 6;
  #pragma unroll
  for (int i = 0; i < 16; ++i) {
    int r = ty + i * 4;  // k offset
    float v = W[(size_t)(kTile + r) * FH + ocTile + tx];
    tile[r][tx] = f2bf(v);
  }
  __syncthreads();
  #pragma unroll
  for (int i = 0; i < 16; ++i) {
    int c = ty + i * 4;              // column offset within tile
    int oc = ocTile + c;
    int gate = oc >> 10, rem = oc & 1023;
    int b = rem >> 3, hcl = rem & 7;
    int r_out = b * 32 + hcl * 4 + gate;
    WT[(size_t)r_out * D_DIM + kTile + tx] = tile[tx][c];
  }
}

// x fp32 -> bf16, one float4 per thread. grid 32768, block 256.
__global__ void cvt_x(const float* __restrict__ x, ushort* __restrict__ xb) {
  size_t i = (size_t)blockIdx.x * blockDim.x + threadIdx.x;
  const float4* x4 = (const float4*)x;
  float4 v = x4[i];
  ushort4 o; o.x = f2bf(v.x); o.y = f2bf(v.y); o.z = f2bf(v.z); o.w = f2bf(v.w);
  ((ushort4*)xb)[i] = o;
}

// h0 fp32 -> bf16 into h_buf0. grid 256, block 256.
__global__ void cvt_h0(const float* __restrict__ h0, ushort* __restrict__ hb) {
  int i = blockIdx.x * blockDim.x + threadIdx.x;
  hb[i] = f2bf(h0[i]);
}

// zero the per-block producer flags (one 128B line per block).
__global__ void zero_flags(unsigned* f) { f[threadIdx.x * 32] = 0u; }

// ---------------------------------------------------------------------------
// xz GEMM: A = x_bf16 [32768][1024], B = WxT_perm [4096][1024] (both K-contig)
// 128x128 tile, BK=64, 256 threads (4 waves as 2x2 of 64x64).
// ---------------------------------------------------------------------------
__global__ __launch_bounds__(256) void gemm_xz(const ushort* __restrict__ A,
                                               const ushort* __restrict__ B,
                                               ushort* __restrict__ xz) {
  __shared__ ushort As[128][72];
  __shared__ ushort Bs[128][72];
  int bid = blockIdx.x;
  int nb = bid & 31, mb = bid >> 5;
  int m0 = mb * 128, n0 = nb * 128;
  int tid = threadIdx.x;
  int lane = tid & 63, w = tid >> 6;
  int wm = w >> 1, wn = w & 1;
  int quad = lane >> 4, l15 = lane & 15;

  f32x4 acc[4][4];
  #pragma unroll
  for (int i = 0; i < 4; ++i)
    #pragma unroll
    for (int j = 0; j < 4; ++j) acc[i][j] = (f32x4)0.f;

  for (int k0 = 0; k0 < D_DIM; k0 += 64) {
    #pragma unroll
    for (int q = 0; q < 4; ++q) {
      int seg = q * 256 + tid;          // 0..1023
      int row = seg >> 3, k8 = seg & 7;
      uint4 va = *(const uint4*)(A + (size_t)(m0 + row) * D_DIM + k0 + k8 * 8);
      *(uint4*)(&As[row][k8 * 8]) = va;
      uint4 vb = *(const uint4*)(B + (size_t)(n0 + row) * D_DIM + k0 + k8 * 8);
      *(uint4*)(&Bs[row][k8 * 8]) = vb;
    }
    __syncthreads();
    #pragma unroll
    for (int kc = 0; kc < 2; ++kc) {
      int krow = kc * 32 + quad * 8;
      short8 a[4], b[4];
      #pragma unroll
      for (int mt = 0; mt < 4; ++mt)
        a[mt] = *(const short8*)(&As[wm * 64 + mt * 16 + l15][krow]);
      #pragma unroll
      for (int nt = 0; nt < 4; ++nt)
        b[nt] = *(const short8*)(&Bs[wn * 64 + nt * 16 + l15][krow]);
      #pragma unroll
      for (int mt = 0; mt < 4; ++mt)
        #pragma unroll
        for (int nt = 0; nt < 4; ++nt)
          acc[mt][nt] = __builtin_amdgcn_mfma_f32_16x16x32_bf16(a[mt], b[nt], acc[mt][nt], 0, 0, 0);
    }
    __syncthreads();
  }
  // epilogue: write bf16 into [t][n][4096]
  #pragma unroll
  for (int mt = 0; mt < 4; ++mt)
    #pragma unroll
    for (int nt = 0; nt < 4; ++nt)
      #pragma unroll
      for (int r = 0; r < 4; ++r) {
        int m = m0 + wm * 64 + mt * 16 + quad * 4 + r;
        int n = n0 + wn * 64 + nt * 16 + l15;
        int t = m & 511, nn = m >> 9;
        xz[(size_t)(t * 64 + nn) * FH + n] = f2bf(acc[mt][nt][r]);
      }
}

// ---------------------------------------------------------------------------
// Persistent cooperative LSTM scan — producer/consumer flag sync (NO grid
// barrier). 256 blocks = 4 row-groups (mg, 16 batch rows) x 64 col-groups
// (cg, 64 permuted gate-cols = 16 h-cols). 4 waves; wave w owns K-slice
// [w*256,(w+1)*256) -> depends on exactly 16 producer blocks (same mg,
// cg = w*16..w*16+15).
//
// Sync protocol (replaces round-5's full-grid barrier = 5 serialized
// L3 trips incl. RMW + 256-wide detection):
//   writer (end of step t):  h stores (coherent dword) -> vmcnt(0) drain
//     -> __syncthreads -> tid0 stores wflag[blk] = t+1 (plain relaxed).
//   reader (start of step t): wave w polls wflag of its 16 producers
//     (lane l15 polls one; wave reconverges when all >= t), compiler
//     "memory" fence, then burst h loads.
// Anti-overwrite with 2 ping-pong buffers is safe: X at step-t write phase
// => X saw wflag >= t for ALL 64 mg-blocks => each finished writing h(t)
// => each finished READING h(t-1) — exactly the buffer X overwrites.
// mg-groups are fully decoupled (jitter absorbs instead of stacking).
//
// Wh slice (64 cols x 1024 K = 128 KiB) staged in LDS once, XOR-swizzled
// (byte ^= (row&7)<<4) so per-(nt,kc) column-slice ds_read_b128 is ~2-way.
// ---------------------------------------------------------------------------
__global__ __launch_bounds__(256, 1) void lstm_scan(
    const ushort* __restrict__ xz,    // [512][64][4096] bf16 (permuted cols)
    const ushort* __restrict__ WhT,   // [4096][1024] bf16 (permuted rows)
    const float*  __restrict__ bias,  // [4096] original order
    ushort* h0buf, ushort* h1buf,     // [64][1024] bf16 ping-pong
    float* __restrict__ out,          // [64][512][1024] fp32
    unsigned* wflag)                  // [256] flags, stride 32 dwords, pre-zeroed
{
  __shared__ ushort whlds[64 * 1024];       // 128 KiB, XOR-swizzled rows
  __shared__ float zpart[4 * 16 * 68];      // [w][m 0..15][col 0..63], stride 68

  const int blk = blockIdx.x;     // 0..255
  const int tid = threadIdx.x;
  const int w = tid >> 6;         // wave = K-slice 0..3
  const int lane = tid & 63;
  const int quad = lane >> 4;
  const int l15 = lane & 15;

  const int mg = blk >> 6;        // 0..3   batch-row group (16 rows)
  const int cg = blk & 63;        // 0..63  col group (64 permuted cols)
  const int m0 = mg * 16;

  // ---- stage Wh slice into LDS once (XOR-swizzled 16B granules) ----
  {
    const ushort* src = WhT + (size_t)(cg * 64) * D_DIM;
    #pragma unroll
    for (int it = 0; it < 32; ++it) {
      int idx = it * 256 + tid;           // 0..8191 chunks of 16B
      int row = idx >> 7;                 // 0..63 (col index)
      int slot = idx & 127;               // 16B slot within the 2048B row
      uint4 v = *(const uint4*)(src + (size_t)row * D_DIM + slot * 8);
      int byteoff = row * 2048 + ((slot * 16) ^ ((row & 7) << 4));
      *(uint4*)((char*)whlds + byteoff) = v;
    }
  }

  // my 16 producer blocks: same mg, cg = w*16 + l15 (lanes 16-63 mirror)
  const unsigned* myflag = &wflag[(mg * 64 + w * 16 + l15) * 32];

  // gate-phase assignment (threads 0..127): row gm 0..15, col-octet gq 0..7
  const int gm = tid >> 3;        // valid for tid < 128
  const int gq = tid & 7;
  const int hc2 = (gq >> 2) * 8 + (gq & 3) * 2;   // local h-col pair base
  float bb[8];
  #pragma unroll
  for (int j = 0; j < 8; ++j)
    bb[j] = bias[(j & 3) * 1024 + cg * 16 + hc2 + (j >> 2)];
  float cst[2] = {0.f, 0.f};

  const ushort* bufs[2] = {h0buf, h1buf};
  __syncthreads();   // whlds ready

  for (int t = 0; t < TT; ++t) {
    const ushort* rb = bufs[t & 1];
    ushort* wb = (ushort*)bufs[(t + 1) & 1];

    // prefetch xz for this thread's gate-phase cols (in flight during poll)
    uint4 xzv;
    if (tid < 128)
      xzv = *(const uint4*)(xz + (size_t)(t * 64 + m0 + gm) * FH + cg * 64 + gq * 8);

    // ---- producer-flag poll: wave reconverges when all 16 flags >= t ----
    // (t=0: condition trivially false -> no iterations; h0 pre-staged)
    while (__hip_atomic_load(myflag, __ATOMIC_RELAXED,
                             __HIP_MEMORY_SCOPE_AGENT) < (unsigned)t) {}
    asm volatile("" ::: "memory");   // keep h loads below the poll

    // ---- burst-issue ALL h loads: 16 x 8B from ONE row base + immediates ----
    ull areg[8][2];
    {
      const ushort* r0 = rb + (size_t)(m0 + l15) * H_DIM + w * 256 + quad * 8;
      #pragma unroll
      for (int kc = 0; kc < 8; ++kc) {
        areg[kc][0] = __hip_atomic_load((const ull*)(r0 + kc * 32),     __ATOMIC_RELAXED, __HIP_MEMORY_SCOPE_AGENT);
        areg[kc][1] = __hip_atomic_load((const ull*)(r0 + kc * 32 + 4), __ATOMIC_RELAXED, __HIP_MEMORY_SCOPE_AGENT);
      }
    }

    f32x4 acc[4];
    #pragma unroll
    for (int nt = 0; nt < 4; ++nt) acc[nt] = (f32x4)0.f;

    #pragma unroll
    for (int kc = 0; kc < 8; ++kc) {
      union { ull u[2]; short8 s; } av;
      av.u[0] = areg[kc][0]; av.u[1] = areg[kc][1];
      const int koff = (w * 512 + kc * 64 + quad * 16) ^ ((l15 & 7) << 4);
      #pragma unroll
      for (int nt = 0; nt < 4; ++nt) {
        short8 bf = *(const short8*)((const char*)whlds + (nt * 16 + l15) * 2048 + koff);
        acc[nt] = __builtin_amdgcn_mfma_f32_16x16x32_bf16(av.s, bf, acc[nt], 0, 0, 0);
      }
    }

    // write K-partials to LDS: zpart[w][m][col], stride 68 -> 2-way (free)
    #pragma unroll
    for (int nt = 0; nt < 4; ++nt)
      #pragma unroll
      for (int r = 0; r < 4; ++r) {
        int m = quad * 4 + r;
        zpart[(w * 16 + m) * 68 + nt * 16 + l15] = acc[nt][r];
      }
    __syncthreads();

    // gate phase on threads 0..127: 8 cols = 2 h-cols x 4 gates
    if (tid < 128) {
      float z[8];
      const ushort* xp = (const ushort*)&xzv;
      #pragma unroll
      for (int j = 0; j < 8; ++j) z[j] = bb[j] + bf2f(xp[j]);
      #pragma unroll
      for (int wv = 0; wv < 4; ++wv) {
        const float4* pp = (const float4*)&zpart[(wv * 16 + gm) * 68 + gq * 8];
        float4 p0 = pp[0], p1 = pp[1];
        z[0] += p0.x; z[1] += p0.y; z[2] += p0.z; z[3] += p0.w;
        z[4] += p1.x; z[5] += p1.y; z[6] += p1.z; z[7] += p1.w;
      }
      ushort hpack[2];
      float hout[2];
      #pragma unroll
      for (int p = 0; p < 2; ++p) {
        float ai = z[p * 4 + 0], af = z[p * 4 + 1], ao = z[p * 4 + 2], ag = z[p * 4 + 3];
        float ig = 1.f / (1.f + __expf(-ai));
        float fg = 1.f / (1.f + __expf(-af));
        float og = 1.f / (1.f + __expf(-ao));
        float gg = 2.f / (1.f + __expf(-2.f * ag)) - 1.f;   // tanh
        float c = fg * cst[p] + ig * gg;
        cst[p] = c;
        float th = 2.f / (1.f + __expf(-2.f * c)) - 1.f;    // tanh
        float h = og * th;
        hout[p] = h; hpack[p] = f2bf(h);
      }
      // h recurrence store: agent-scope write-through dword (reaches L3)
      unsigned hbits = (unsigned)hpack[0] | ((unsigned)hpack[1] << 16);
      __hip_atomic_store((unsigned*)(wb + (size_t)(m0 + gm) * H_DIM + cg * 16 + hc2), hbits,
                         __ATOMIC_RELAXED, __HIP_MEMORY_SCOPE_AGENT);
      // output store: plain (nobody reads it during the scan)
      float2 ho; ho.x = hout[0]; ho.y = hout[1];
      *(float2*)(out + ((size_t)(m0 + gm) * TT + t) * H_DIM + cg * 16 + hc2) = ho;
    }

    // ---- publish: drain h stores, then advertise step completion ----
    asm volatile("s_waitcnt vmcnt(0)" ::: "memory");
    __syncthreads();   // all threads' h stores drained; zpart reads done
    if (tid == 0)
      __hip_atomic_store(&wflag[blk * 32], (unsigned)(t + 1),
                         __ATOMIC_RELAXED, __HIP_MEMORY_SCOPE_AGENT);
  }
}

// ---------------------------------------------------------------------------
extern "C" void kernel_launch(void* const* d_in, const int* in_sizes, int n_in,
                              void* d_out, int out_size, void* d_ws, size_t ws_size,
                              hipStream_t stream) {
  const float* x  = (const float*)d_in[0];   // 64*512*1024
  const float* h0 = (const float*)d_in[1];   // 64*1024
  const float* Wx = (const float*)d_in[2];   // 1024*4096
  const float* Wh = (const float*)d_in[3];   // 1024*4096
  const float* b  = (const float*)d_in[4];   // 4096
  float* out = (float*)d_out;

  char* ws = (char*)d_ws;
  ushort* xz    = (ushort*)(ws + 0);                    // 268,435,456 B
  ushort* xb    = (ushort*)(ws + 268435456);            //  67,108,864 B (dead after gemm_xz)
  ushort* WxT   = (ushort*)(ws + 335544320);            //   8,388,608 B
  ushort* WhT   = (ushort*)(ws + 343932928);            //   8,388,608 B
  ushort* h0buf = (ushort*)(ws + 352321536);            //     131,072 B
  ushort* h1buf = (ushort*)(ws + 352452608);            //     131,072 B
  unsigned* wflag = (unsigned*)(ws + 268435456);        // 32 KB flags (aliases dead xb)

  transpose_perm<<<dim3(64, 16), 256, 0, stream>>>(Wx, WxT);
  transpose_perm<<<dim3(64, 16), 256, 0, stream>>>(Wh, WhT);
  cvt_x<<<32768, 256, 0, stream>>>(x, xb);
  cvt_h0<<<256, 256, 0, stream>>>(h0, h0buf);
  gemm_xz<<<8192, 256, 0, stream>>>(xb, WxT, xz);
  zero_flags<<<1, SCAN_BLOCKS, 0, stream>>>(wflag);   // after gemm_xz: xb dead

  void* args[] = {(void*)&xz, (void*)&WhT, (void*)&b, (void*)&h0buf, (void*)&h1buf,
                  (void*)&out, (void*)&wflag};
  hipLaunchCooperativeKernel((const void*)lstm_scan, dim3(SCAN_BLOCKS), dim3(256), args, 0, stream);
}